// Round 4
// baseline (289.008 us; speedup 1.0000x reference)
//
#include <hip/hip_runtime.h>
#include <stdint.h>
#include <math.h>

typedef unsigned int u32;
typedef __bf16 bf16x8 __attribute__((ext_vector_type(8)));
typedef float  f32x4  __attribute__((ext_vector_type(4)));
typedef float  f32x16 __attribute__((ext_vector_type(16)));
typedef unsigned int u32x4 __attribute__((ext_vector_type(4)));
typedef unsigned short u16x4 __attribute__((ext_vector_type(4)));
typedef unsigned short u16x8 __attribute__((ext_vector_type(8)));

#define DEV __device__ __forceinline__

DEV unsigned short f2b(float f) {
  u32 x = __builtin_bit_cast(u32, f);
  u32 r = (x + 0x7fffu + ((x >> 16) & 1u)) >> 16;
  return (unsigned short)r;
}
DEV float b2f(unsigned short u) { return __builtin_bit_cast(float, ((u32)u) << 16); }

DEV u32 cvtpk_bf16(float lo, float hi) {
  u32 r;
  asm("v_cvt_pk_bf16_f32 %0, %1, %2" : "=v"(r) : "v"(lo), "v"(hi));
  return r;
}
DEV void pl32swap(u32& a, u32& b) {
  asm("v_permlane32_swap_b32 %0, %1" : "+v"(a), "+v"(b));
}

// async global->LDS, 16B per lane. LDS dest = wave-uniform base + lane*16.
DEV void gl2lds16(const void* g, void* l) {
  __builtin_amdgcn_global_load_lds((const __attribute__((address_space(1))) u32*)g,
                                   (__attribute__((address_space(3))) u32*)l, 16, 0, 0);
}

// ---------------- prep kernels ----------------

__global__ void rope_tables_k(float* __restrict__ ct, float* __restrict__ st) {
  int s = blockIdx.x;          // 0..2047
  int d = threadIdx.x;         // 0..63
  float inv = powf(10000.0f, -(float)d / 64.0f);
  float a = (float)s * inv;
  ct[s * 64 + d] = cosf(a);
  st[s * 64 + d] = sinf(a);
}

// X f32 [Mtot][2048] -> packed bf16 [64][Mtot][32]
__global__ void packX_k(const float* __restrict__ in, unsigned short* __restrict__ out,
                        int Mtot) {
  int i = blockIdx.x * blockDim.x + threadIdx.x;   // one thread per 8 elems
  int k8 = i & 255;          // 2048/8 octets per row
  int m = i >> 8;
  if (m >= Mtot) return;
  const float4* p = (const float4*)(in + (size_t)m * 2048 + (k8 << 3));
  float4 v0 = p[0], v1 = p[1];
  u16x8 r = { f2b(v0.x), f2b(v0.y), f2b(v0.z), f2b(v0.w),
              f2b(v1.x), f2b(v1.y), f2b(v1.z), f2b(v1.w) };
  int kt = k8 >> 2;          // (k8*8)>>5
  int ko = (k8 & 3) << 3;    // (k8*8)&31
  *(u16x8*)(out + ((size_t)kt * Mtot + m) * 32 + ko) = r;
}

// W f32 [2048][Nd] -> packed bf16 [64][Ncat][32] (transposed), cols at ncOff
__global__ void packW_k(const float* __restrict__ in, unsigned short* __restrict__ out,
                        int Nd, int Ncat, int ncOff) {
  __shared__ float t[32][33];
  int n0 = blockIdx.x << 5, k0 = blockIdx.y << 5;
  int tx = threadIdx.x, ty = threadIdx.y;  // 32 x 8
  for (int i = ty; i < 32; i += 8) t[i][tx] = in[(size_t)(k0 + i) * Nd + n0 + tx];
  __syncthreads();
  for (int i = ty; i < 32; i += 8)
    out[((size_t)(k0 >> 5) * Ncat + ncOff + n0 + i) * 32 + tx] = f2b(t[tx][i]);
}

// vectorized RoPE: each thread handles 8 d-values (pair d, d+64), 16B loads
template <bool SC>
__global__ void rope8_k(unsigned short* __restrict__ p, const float* __restrict__ ct,
                        const float* __restrict__ st, int total) {
  int i = blockIdx.x * blockDim.x + threadIdx.x;
  if (i >= total) return;
  int j = i & 7;               // which 8-wide d block in [0,64)
  int s = (i >> 3) & 2047;
  int bh = i >> 14;
  size_t base = ((size_t)bh * 2048 + s) * 128 + (j << 3);
  u16x8 a = *(const u16x8*)(p + base);
  u16x8 b = *(const u16x8*)(p + base + 64);
  const float* cp = ct + s * 64 + (j << 3);
  const float* sp = st + s * 64 + (j << 3);
  u16x8 oa, ob;
#pragma unroll
  for (int e = 0; e < 8; ++e) {
    float x1 = b2f(a[e]), x2 = b2f(b[e]);
    float c = cp[e], sn = sp[e];
    float o1 = x1 * c - x2 * sn;
    float o2 = x2 * c + x1 * sn;
    if (SC) { o1 *= 0.08838834764831845f; o2 *= 0.08838834764831845f; }
    oa[e] = f2b(o1);
    ob[e] = f2b(o2);
  }
  *(u16x8*)(p + base) = oa;
  *(u16x8*)(p + base + 64) = ob;
}

// ---------------- GEMM: 8-phase counted-vmcnt pipeline (m201-style) ----------------
// A packed [K/32][Mtot][32] bf16, B packed [K/32][Ntot][32] bf16. K = 2048.
// 512 threads = 8 waves (2M x 4N). BM = MF*32 (MF=8 -> 256, MF=4 -> 128), BN = 256.
// LDS: 2 buffers per operand, each buffer = 2 K-half panels [rows][32] (64B rows,
// XOR-swizzled via pre-permuted global source). Per K-tile (BK=64): 4 phases,
// each {ds_read 4-8 x b128 | stage one 16KB quarter | (vmcnt(4/3) at p1,p3) |
// barrier | lgkmcnt(0) | setprio(1) MFMAx(MF/2*4) setprio(0) | barrier}.
// MODE 0: fp32 out[row*Ntot+col].  MODE 3: fused QKV epilogue.
template <int MF, int MODE>
__global__ __launch_bounds__(512, 2) void gemm8p_k(
    const unsigned short* __restrict__ Ap, const unsigned short* __restrict__ Bp,
    float* __restrict__ outF, unsigned short* __restrict__ outQ,
    unsigned short* __restrict__ outK, unsigned short* __restrict__ outV,
    const float* __restrict__ bq_, const float* __restrict__ bk_,
    const float* __restrict__ bv_, int Mtot, int Ntot, int GX) {
  constexpr int BM = MF * 32;
  constexpr int NKT = 32;                   // K=2048, BK=64
  __shared__ alignas(16) unsigned short Al[2 * BM * 64];
  __shared__ alignas(16) unsigned short Bl[2 * 256 * 64];

  const int tid = threadIdx.x, lane = tid & 63, wid = tid >> 6;
  const int wr = wid >> 2, wc = wid & 3;
  const int cl = lane & 15, g = lane >> 4;

  const int nwg = gridDim.x;                // multiple of 8
  const int w0 = blockIdx.x;
  const int sw = (w0 & 7) * (nwg >> 3) + (w0 >> 3);   // XCD-contiguous chunks
  const int bx = sw % GX, by = sw / GX;
  const int row0 = by * BM, col0 = bx << 8;

  f32x4 acc[MF][4];
#pragma unroll
  for (int m = 0; m < MF; ++m)
#pragma unroll
    for (int n = 0; n < 4; ++n) acc[m][n] = (f32x4){0.f, 0.f, 0.f, 0.f};

  bf16x8 bf4[4];

  // stage quarter q of K-tile t into buffer t&1. q: 0=A-kh0,1=B-kh0,2=A-kh1,3=B-kh1
  auto stageQ = [&](int t, int q) {
    const int buf = t & 1;
    const int kh = q >> 1;
    const bool isB = q & 1;
    const int RT = isB ? 256 : BM;
    const unsigned short* src = isB ? Bp : Ap;
    unsigned short* lds = (isB ? Bl : Al) + buf * (RT * 64) + kh * (RT * 32);
    const size_t qb = ((size_t)(t * 2 + kh) * (isB ? Ntot : Mtot) + (isB ? col0 : row0)) * 32;
    const int nc = RT >> 7;                 // calls per thread (1 or 2)
#pragma unroll
    for (int i = 0; i < 2; ++i) {
      if (i < nc) {
        int c = wid + (i << 3);             // 1KB chunk = 16 rows x 64B, contiguous
        int row = (c << 4) + (lane >> 2);
        int sl = (lane & 3) ^ ((row >> 1) & 3);   // pre-permuted source = LDS swizzle
        gl2lds16(src + qb + row * 32 + (sl << 3), lds + (c << 9) + (lane << 3));
      }
    }
  };

  // one phase. wmode: 0 none, 1 vmcnt(4|3), 2 vmcnt(0)
#define PHASE(T, KC, MH, LOADB, Q, WMODE)                                              \
  do {                                                                                 \
    const int buf_ = (T) & 1;                                                          \
    bf16x8 a4[MF / 2];                                                                 \
    _Pragma("unroll") for (int m = 0; m < MF / 2; ++m) {                               \
      int row = wr * (MF * 16) + ((MH) * (MF / 2) + m) * 16 + cl;                      \
      a4[m] = *(const bf16x8*)&Al[buf_ * (BM * 64) + (KC) * (BM * 32) + row * 32 +     \
                                  ((g ^ ((row >> 1) & 3)) << 3)];                      \
    }                                                                                  \
    if (LOADB) {                                                                       \
      _Pragma("unroll") for (int n = 0; n < 4; ++n) {                                  \
        int row = (wc << 6) + (n << 4) + cl;                                           \
        bf4[n] = *(const bf16x8*)&Bl[buf_ * 16384 + (KC) * 8192 + row * 32 +           \
                                     ((g ^ ((row >> 1) & 3)) << 3)];                   \
      }                                                                                \
    }                                                                                  \
    if ((Q) >= 0) stageQ((T) + 1, (Q));                                                \
    if ((WMODE) == 1) {                                                                \
      if (MF == 8) asm volatile("s_waitcnt vmcnt(4)" ::: "memory");                    \
      else         asm volatile("s_waitcnt vmcnt(3)" ::: "memory");                    \
    } else if ((WMODE) == 2) {                                                         \
      asm volatile("s_waitcnt vmcnt(0)" ::: "memory");                                 \
    }                                                                                  \
    __builtin_amdgcn_s_barrier();                                                      \
    asm volatile("s_waitcnt lgkmcnt(0)" ::: "memory");                                 \
    __builtin_amdgcn_sched_barrier(0);                                                 \
    __builtin_amdgcn_s_setprio(1);                                                     \
    _Pragma("unroll") for (int m = 0; m < MF / 2; ++m)                                 \
    _Pragma("unroll") for (int n = 0; n < 4; ++n)                                      \
        acc[(MH) * (MF / 2) + m][n] = __builtin_amdgcn_mfma_f32_16x16x32_bf16(         \
            a4[m], bf4[n], acc[(MH) * (MF / 2) + m][n], 0, 0, 0);                      \
    __builtin_amdgcn_s_setprio(0);                                                     \
    __builtin_amdgcn_s_barrier();                                                      \
  } while (0)

  // prologue: stage all of K-tile 0, drain, barrier
  stageQ(0, 0); stageQ(0, 1); stageQ(0, 2); stageQ(0, 3);
  asm volatile("s_waitcnt vmcnt(0)" ::: "memory");
  __builtin_amdgcn_s_barrier();
  __builtin_amdgcn_sched_barrier(0);

  for (int t = 0; t < NKT - 1; ++t) {
    PHASE(t, 0, 0, true,  0, 0);
    PHASE(t, 0, 1, false, 1, 1);
    PHASE(t, 1, 1, true,  2, 0);
    PHASE(t, 1, 0, false, 3, 1);
  }
  {
    const int T = NKT - 1;
    PHASE(T, 0, 0, true,  -1, 0);
    PHASE(T, 0, 1, false, -1, 2);
    PHASE(T, 1, 1, true,  -1, 0);
    PHASE(T, 1, 0, false, -1, 0);
  }
#undef PHASE

  // epilogue
#pragma unroll
  for (int m = 0; m < MF; ++m) {
    int rbase = row0 + wr * (MF * 16) + (m << 4) + (g << 2);
#pragma unroll
    for (int n = 0; n < 4; ++n) {
      int col = col0 + (wc << 6) + (n << 4) + cl;
#pragma unroll
      for (int r = 0; r < 4; ++r) {
        float v = acc[m][n][r];
        int rr = rbase + r;
        if constexpr (MODE == 0) {
          outF[(size_t)rr * Ntot + col] = v;
        } else {  // MODE 3
          int bb = rr >> 11, ss = rr & 2047;
          if (col < 2048) {
            int hh = col >> 7, d = col & 127;
            outQ[((((size_t)bb << 4) + hh) * 2048 + ss) * 128 + d] = f2b(v + bq_[col]);
          } else if (col < 2560) {
            int c2 = col - 2048, kk = c2 >> 7, d = c2 & 127;
            outK[((((size_t)bb << 2) + kk) * 2048 + ss) * 128 + d] = f2b(v + bk_[c2]);
          } else {
            int c2 = col - 2560, kk = c2 >> 7, d = c2 & 127;
            outV[((((size_t)bb << 2) + kk) * 128 + d) * 2048 + ss] = f2b(v + bv_[c2]);
          }
        }
      }
    }
  }
}

// ---------------- flash attention: swapped QK^T, 32x32x16 MFMA ----------------
// Qb [B][16][S][128] (pre-scaled, RoPE'd), Kb [B][4][S][128], Vt [B][4][128][S]
// AOp packed [64][B*S][32] bf16 (feeds O-proj directly).
// 256 threads = 4 waves x 32 q-rows, KVBLK=64.
__global__ __launch_bounds__(256, 2) void attn2_k(
    const unsigned short* __restrict__ Qb, const unsigned short* __restrict__ Kb,
    const unsigned short* __restrict__ Vt, unsigned short* __restrict__ AOp) {
  __shared__ alignas(16) unsigned short Ks[2][64 * 128];   // [kv][d], slot^=(row&15)
  __shared__ alignas(16) unsigned short Vs[2][128 * 64];   // [d][kv], slot^=(row&7)

  const int tid = threadIdx.x, lane = tid & 63, wid = tid >> 6;
  const int hw = blockIdx.x;
  const int work = ((hw & 7) << 6) | (hw >> 3);
  const int qblk = work & 15, bh = work >> 4;
  const int b = bh >> 4, h = bh & 15, kvh = h >> 2;
  const int q0 = qblk << 7;
  const int cl = lane & 31, hi = lane >> 5;

  const unsigned short* Qp = Qb + ((size_t)(b * 16 + h) << 11) * 128;
  const unsigned short* Kp = Kb + ((size_t)(b * 4 + kvh) << 11) * 128;
  const unsigned short* Vp = Vt + ((size_t)(b * 4 + kvh) << 7) * 2048;

  const int qrow = q0 + (wid << 5) + cl;
  bf16x8 qf[8];
#pragma unroll
  for (int c = 0; c < 8; ++c)
    qf[c] = *(const bf16x8*)(Qp + (size_t)qrow * 128 + (c << 4) + (hi << 3));

  f32x16 o[4];
#pragma unroll
  for (int dt = 0; dt < 4; ++dt)
#pragma unroll
    for (int r = 0; r < 16; ++r) o[dt][r] = 0.f;
  float m = -3e38f, l = 0.f;

  auto stage = [&](int t, int buf) {
    const int kv0 = t << 6;
#pragma unroll
    for (int i = 0; i < 4; ++i) {   // K: wave stages 16 rows x 256B
      int row = (wid << 4) + (i << 2) + (lane >> 4);
      int sl = (lane & 15) ^ (row & 15);
      gl2lds16(Kp + ((size_t)(kv0 + row) << 7) + (sl << 3),
               &Ks[buf][(wid << 11) + (i << 9) + (lane << 3)]);
    }
#pragma unroll
    for (int i = 0; i < 4; ++i) {   // V^T: wave stages 32 rows x 128B
      int row = (wid << 5) + (i << 3) + (lane >> 3);
      int sl = (lane & 7) ^ (row & 7);
      gl2lds16(Vp + ((size_t)row << 11) + kv0 + (sl << 3),
               &Vs[buf][(wid << 11) + (i << 9) + (lane << 3)]);
    }
  };

  auto pack8 = [&](float a0, float a1, float a2, float a3,
                   float a4, float a5, float a6, float a7) -> u32x4 {
    u32 x0 = cvtpk_bf16(a0, a1);
    u32 y0 = cvtpk_bf16(a4, a5);
    u32 x1 = cvtpk_bf16(a2, a3);
    u32 y1 = cvtpk_bf16(a6, a7);
    pl32swap(x0, y0);
    pl32swap(x1, y1);
    return (u32x4){x0, x1, y0, y1};
  };

  stage(0, 0);
  __syncthreads();

  for (int t = 0; t < 32; ++t) {
    const int buf = t & 1;
    if (t + 1 < 32) stage(t + 1, buf ^ 1);

    f32x16 s0, s1;
#pragma unroll
    for (int r = 0; r < 16; ++r) { s0[r] = 0.f; s1[r] = 0.f; }
#pragma unroll
    for (int c = 0; c < 8; ++c) {
      int sl0 = ((c << 1) + hi) ^ (cl & 15);
      bf16x8 kf0 = *(const bf16x8*)&Ks[buf][(cl << 7) + (sl0 << 3)];
      s0 = __builtin_amdgcn_mfma_f32_32x32x16_bf16(kf0, qf[c], s0, 0, 0, 0);
    }
#pragma unroll
    for (int c = 0; c < 8; ++c) {
      int row = 32 + cl;
      int sl1 = ((c << 1) + hi) ^ (row & 15);
      bf16x8 kf1 = *(const bf16x8*)&Ks[buf][(row << 7) + (sl1 << 3)];
      s1 = __builtin_amdgcn_mfma_f32_32x32x16_bf16(kf1, qf[c], s1, 0, 0, 0);
    }

    float mx = s0[0];
#pragma unroll
    for (int r = 1; r < 16; ++r) mx = fmaxf(mx, s0[r]);
#pragma unroll
    for (int r = 0; r < 16; ++r) mx = fmaxf(mx, s1[r]);
    mx = fmaxf(mx, __shfl_xor(mx, 32));

    if (!__all(mx <= m + 8.0f)) {
      float mn = fmaxf(m, mx);
      float al = __expf(m - mn);
      m = mn;
      l *= al;
#pragma unroll
      for (int dt = 0; dt < 4; ++dt)
#pragma unroll
        for (int r = 0; r < 16; ++r) o[dt][r] *= al;
    }

    float sum = 0.f;
#pragma unroll
    for (int r = 0; r < 16; ++r) { s0[r] = __expf(s0[r] - m); sum += s0[r]; }
#pragma unroll
    for (int r = 0; r < 16; ++r) { s1[r] = __expf(s1[r] - m); sum += s1[r]; }
    l += sum;

    u32x4 w0 = pack8(s0[0], s0[1], s0[2], s0[3], s0[4], s0[5], s0[6], s0[7]);
    u32x4 w1 = pack8(s0[8], s0[9], s0[10], s0[11], s0[12], s0[13], s0[14], s0[15]);
    u32x4 w2 = pack8(s1[0], s1[1], s1[2], s1[3], s1[4], s1[5], s1[6], s1[7]);
    u32x4 w3 = pack8(s1[8], s1[9], s1[10], s1[11], s1[12], s1[13], s1[14], s1[15]);
    bf16x8 pa0 = __builtin_bit_cast(bf16x8, w0);
    bf16x8 pa1 = __builtin_bit_cast(bf16x8, w1);
    bf16x8 pa2 = __builtin_bit_cast(bf16x8, w2);
    bf16x8 pa3 = __builtin_bit_cast(bf16x8, w3);

#pragma unroll
    for (int dt = 0; dt < 4; ++dt) {
      int row = (dt << 5) + cl;
      int sb = row << 6;
      int rx = row & 7;
      bf16x8 vf0 = *(const bf16x8*)&Vs[buf][sb + (((hi) ^ rx) << 3)];
      o[dt] = __builtin_amdgcn_mfma_f32_32x32x16_bf16(vf0, pa0, o[dt], 0, 0, 0);
      bf16x8 vf1 = *(const bf16x8*)&Vs[buf][sb + (((2 + hi) ^ rx) << 3)];
      o[dt] = __builtin_amdgcn_mfma_f32_32x32x16_bf16(vf1, pa1, o[dt], 0, 0, 0);
      bf16x8 vf2 = *(const bf16x8*)&Vs[buf][sb + (((4 + hi) ^ rx) << 3)];
      o[dt] = __builtin_amdgcn_mfma_f32_32x32x16_bf16(vf2, pa2, o[dt], 0, 0, 0);
      bf16x8 vf3 = *(const bf16x8*)&Vs[buf][sb + (((6 + hi) ^ rx) << 3)];
      o[dt] = __builtin_amdgcn_mfma_f32_32x32x16_bf16(vf3, pa3, o[dt], 0, 0, 0);
    }
    __syncthreads();
  }

  // write packed AO: feature c = h*128 + dt*32 + rq*8 + hi*4 + j -> panel h*4+dt
  float inv = 1.0f / (l + __shfl_xor(l, 32));
  const int rowi = b * 2048 + qrow;
#pragma unroll
  for (int dt = 0; dt < 4; ++dt) {
    unsigned short* base = AOp + (((size_t)((h << 2) + dt)) * 4096 + rowi) * 32;
#pragma unroll
    for (int rq = 0; rq < 4; ++rq) {
      u16x4 pk = { f2b(o[dt][(rq << 2) + 0] * inv), f2b(o[dt][(rq << 2) + 1] * inv),
                   f2b(o[dt][(rq << 2) + 2] * inv), f2b(o[dt][(rq << 2) + 3] * inv) };
      *(u16x4*)(base + (rq << 3) + (hi << 2)) = pk;
    }
  }
}

// ---------------- launch ----------------
extern "C" void kernel_launch(void* const* d_in, const int* in_sizes, int n_in,
                              void* d_out, int out_size, void* d_ws, size_t ws_size,
                              hipStream_t stream) {
  const float* X  = (const float*)d_in[0];
  const float* Wq = (const float*)d_in[1];
  const float* bq = (const float*)d_in[2];
  const float* Wk = (const float*)d_in[3];
  const float* bk = (const float*)d_in[4];
  const float* Wv = (const float*)d_in[5];
  const float* bv = (const float*)d_in[6];
  const float* Wo = (const float*)d_in[7];
  float* out = (float*)d_out;

  char* ws = (char*)d_ws;
  size_t off = 0;
  auto alloc = [&](size_t bytes) {
    char* p = ws + off;
    off += (bytes + 255) & ~(size_t)255;
    return p;
  };
  unsigned short* Xp   = (unsigned short*)alloc(4096ull * 2048 * 2);   // packed [64][4096][32]
  unsigned short* Wcat = (unsigned short*)alloc(3072ull * 2048 * 2);   // packed [64][3072][32]
  unsigned short* Wop  = (unsigned short*)alloc(2048ull * 2048 * 2);   // packed [64][2048][32]
  unsigned short* Qb   = (unsigned short*)alloc(2ull * 16 * 2048 * 128 * 2);
  unsigned short* Kb   = (unsigned short*)alloc(2ull * 4 * 2048 * 128 * 2);
  unsigned short* Vt   = (unsigned short*)alloc(2ull * 4 * 128 * 2048 * 2);
  unsigned short* AOp  = (unsigned short*)alloc(4096ull * 2048 * 2);   // packed [64][4096][32]
  float* ctab = (float*)alloc(2048ull * 64 * 4);
  float* stab = (float*)alloc(2048ull * 64 * 4);

  rope_tables_k<<<dim3(2048), dim3(64), 0, stream>>>(ctab, stab);
  packX_k<<<dim3(4096), dim3(256), 0, stream>>>(X, Xp, 4096);
  packW_k<<<dim3(64, 64), dim3(32, 8), 0, stream>>>(Wq, Wcat, 2048, 3072, 0);
  packW_k<<<dim3(16, 64), dim3(32, 8), 0, stream>>>(Wk, Wcat, 512, 3072, 2048);
  packW_k<<<dim3(16, 64), dim3(32, 8), 0, stream>>>(Wv, Wcat, 512, 3072, 2560);
  packW_k<<<dim3(64, 64), dim3(32, 8), 0, stream>>>(Wo, Wop, 2048, 2048, 0);

  // fused QKV projection: M=4096, N=3072, K=2048. BM=BN=256 -> 192 blocks.
  gemm8p_k<8, 3><<<dim3(192), dim3(512), 0, stream>>>(
      Xp, Wcat, nullptr, Qb, Kb, Vt, bq, bk, bv, 4096, 3072, 12);

  rope8_k<true><<<dim3(2048), dim3(256), 0, stream>>>(Qb, ctab, stab, 524288);
  rope8_k<false><<<dim3(512), dim3(256), 0, stream>>>(Kb, ctab, stab, 131072);

  attn2_k<<<dim3(512), dim3(256), 0, stream>>>(Qb, Kb, Vt, AOp);

  // O projection: M=4096, N=2048, K=2048. BM=128, BN=256 -> 256 blocks (1/CU).
  gemm8p_k<4, 0><<<dim3(256), dim3(512), 0, stream>>>(
      AOp, Wop, out, nullptr, nullptr, nullptr, nullptr, nullptr, nullptr, 4096, 2048, 8);
}

// Round 5
// 288.290 us; speedup vs baseline: 1.0025x; 1.0025x over previous
//
#include <hip/hip_runtime.h>
#include <stdint.h>
#include <math.h>

typedef unsigned int u32;
typedef __bf16 bf16x8 __attribute__((ext_vector_type(8)));
typedef float  f32x4  __attribute__((ext_vector_type(4)));
typedef float  f32x16 __attribute__((ext_vector_type(16)));
typedef unsigned int u32x4 __attribute__((ext_vector_type(4)));
typedef unsigned short u16x4 __attribute__((ext_vector_type(4)));
typedef unsigned short u16x8 __attribute__((ext_vector_type(8)));

#define DEV __device__ __forceinline__

DEV unsigned short f2b(float f) {
  u32 x = __builtin_bit_cast(u32, f);
  u32 r = (x + 0x7fffu + ((x >> 16) & 1u)) >> 16;
  return (unsigned short)r;
}
DEV float b2f(unsigned short u) { return __builtin_bit_cast(float, ((u32)u) << 16); }

DEV u32 cvtpk_bf16(float lo, float hi) {
  u32 r;
  asm("v_cvt_pk_bf16_f32 %0, %1, %2" : "=v"(r) : "v"(lo), "v"(hi));
  return r;
}
DEV void pl32swap(u32& a, u32& b) {
  asm("v_permlane32_swap_b32 %0, %1" : "+v"(a), "+v"(b));
}

// async global->LDS, 16B per lane. LDS dest = wave-uniform base + lane*16.
DEV void gl2lds16(const void* g, void* l) {
  __builtin_amdgcn_global_load_lds((const __attribute__((address_space(1))) u32*)g,
                                   (__attribute__((address_space(3))) u32*)l, 16, 0, 0);
}

// ---------------- prep kernels ----------------

__global__ void rope_tables_k(float* __restrict__ ct, float* __restrict__ st) {
  int s = blockIdx.x;          // 0..2047
  int d = threadIdx.x;         // 0..63
  float inv = powf(10000.0f, -(float)d / 64.0f);
  float a = (float)s * inv;
  ct[s * 64 + d] = cosf(a);
  st[s * 64 + d] = sinf(a);
}

// X f32 [Mtot][2048] -> packed bf16 [64][Mtot][32]
__global__ void packX_k(const float* __restrict__ in, unsigned short* __restrict__ out,
                        int Mtot) {
  int i = blockIdx.x * blockDim.x + threadIdx.x;   // one thread per 8 elems
  int k8 = i & 255;          // 2048/8 octets per row
  int m = i >> 8;
  if (m >= Mtot) return;
  const float4* p = (const float4*)(in + (size_t)m * 2048 + (k8 << 3));
  float4 v0 = p[0], v1 = p[1];
  u16x8 r = { f2b(v0.x), f2b(v0.y), f2b(v0.z), f2b(v0.w),
              f2b(v1.x), f2b(v1.y), f2b(v1.z), f2b(v1.w) };
  int kt = k8 >> 2;          // (k8*8)>>5
  int ko = (k8 & 3) << 3;    // (k8*8)&31
  *(u16x8*)(out + ((size_t)kt * Mtot + m) * 32 + ko) = r;
}

// W f32 [2048][Nd] -> packed bf16 [64][Ncat][32] (transposed), cols at ncOff
__global__ void packW_k(const float* __restrict__ in, unsigned short* __restrict__ out,
                        int Nd, int Ncat, int ncOff) {
  __shared__ float t[32][33];
  int n0 = blockIdx.x << 5, k0 = blockIdx.y << 5;
  int tx = threadIdx.x, ty = threadIdx.y;  // 32 x 8
  for (int i = ty; i < 32; i += 8) t[i][tx] = in[(size_t)(k0 + i) * Nd + n0 + tx];
  __syncthreads();
  for (int i = ty; i < 32; i += 8)
    out[((size_t)(k0 >> 5) * Ncat + ncOff + n0 + i) * 32 + tx] = f2b(t[tx][i]);
}

// vectorized RoPE: each thread handles 8 d-values (pair d, d+64), 16B loads
template <bool SC>
__global__ void rope8_k(unsigned short* __restrict__ p, const float* __restrict__ ct,
                        const float* __restrict__ st, int total) {
  int i = blockIdx.x * blockDim.x + threadIdx.x;
  if (i >= total) return;
  int j = i & 7;               // which 8-wide d block in [0,64)
  int s = (i >> 3) & 2047;
  int bh = i >> 14;
  size_t base = ((size_t)bh * 2048 + s) * 128 + (j << 3);
  u16x8 a = *(const u16x8*)(p + base);
  u16x8 b = *(const u16x8*)(p + base + 64);
  const float* cp = ct + s * 64 + (j << 3);
  const float* sp = st + s * 64 + (j << 3);
  u16x8 oa, ob;
#pragma unroll
  for (int e = 0; e < 8; ++e) {
    float x1 = b2f(a[e]), x2 = b2f(b[e]);
    float c = cp[e], sn = sp[e];
    float o1 = x1 * c - x2 * sn;
    float o2 = x2 * c + x1 * sn;
    if (SC) { o1 *= 0.08838834764831845f; o2 *= 0.08838834764831845f; }
    oa[e] = f2b(o1);
    ob[e] = f2b(o2);
  }
  *(u16x8*)(p + base) = oa;
  *(u16x8*)(p + base + 64) = ob;
}

// ---------------- GEMM: 8-phase counted-vmcnt pipeline (m201-style) ----------------
// A packed [K/32][Mtot][32] bf16, B packed [K/32][Ntot][32] bf16. K = 2048.
// 512 threads = 8 waves (2M x 4N). BM = MF*32 (8 -> 256, 4 -> 128), BN = 256.
// Per K-tile (BK=64): 4 phases, each {ds_read 2-12 x b128 | stage one quarter
// (1-2 gl2lds/thread) | counted vmcnt at ph1,ph3 (never 0 mid-loop) | barrier |
// setprio(1) MFMA setprio(0) | barrier}. No sched_barrier / forced lgkmcnt:
// the compiler tracks ds_read->MFMA deps itself and keeps interleave freedom.
// Race-safety: writes go to buf (t+1)&1 while reads hit buf t&1; consumer
// ds_reads can't hoist above the vmcnt asm ("memory" clobber).
// MODE 0: fp32 out[row*Ntot+col].  MODE 3: fused QKV epilogue.
template <int MF, int MODE>
__global__ __launch_bounds__(512, 2) void gemm8p_k(
    const unsigned short* __restrict__ Ap, const unsigned short* __restrict__ Bp,
    float* __restrict__ outF, unsigned short* __restrict__ outQ,
    unsigned short* __restrict__ outK, unsigned short* __restrict__ outV,
    const float* __restrict__ bq_, const float* __restrict__ bk_,
    const float* __restrict__ bv_, int Mtot, int Ntot, int GX) {
  constexpr int BM = MF * 32;
  constexpr int NKT = 32;                   // K=2048, BK=64
  __shared__ alignas(16) unsigned short Al[2 * BM * 64];
  __shared__ alignas(16) unsigned short Bl[2 * 256 * 64];

  const int tid = threadIdx.x, lane = tid & 63, wid = tid >> 6;
  const int wr = wid >> 2, wc = wid & 3;
  const int cl = lane & 15, g = lane >> 4;

  const int nwg = gridDim.x;                // multiple of 8
  const int w0 = blockIdx.x;
  const int sw = (w0 & 7) * (nwg >> 3) + (w0 >> 3);   // XCD-contiguous chunks
  const int bx = sw % GX, by = sw / GX;
  const int row0 = by * BM, col0 = bx << 8;

  f32x4 acc[MF][4];
#pragma unroll
  for (int m = 0; m < MF; ++m)
#pragma unroll
    for (int n = 0; n < 4; ++n) acc[m][n] = (f32x4){0.f, 0.f, 0.f, 0.f};

  bf16x8 bf4[4];

// stage quarter Q (compile-time) of K-tile T into buffer T&1.
// Q: 0=A-kh0, 1=B-kh0, 2=A-kh1, 3=B-kh1. Each 1KB chunk = 16 rows x 64B contiguous.
#define STAGEQ(T, Q)                                                                    \
  do {                                                                                  \
    constexpr int kh_ = (Q) >> 1;                                                       \
    constexpr bool isB_ = ((Q) & 1) != 0;                                               \
    constexpr int RT_ = isB_ ? 256 : BM;                                                \
    const unsigned short* src_ = isB_ ? Bp : Ap;                                        \
    unsigned short* lds_ = (isB_ ? Bl : Al) + ((T) & 1) * (RT_ * 64) + kh_ * (RT_ * 32);\
    const size_t qb_ = ((size_t)((T) * 2 + kh_) * (isB_ ? Ntot : Mtot) +                \
                        (isB_ ? col0 : row0)) * 32;                                     \
    _Pragma("unroll") for (int i_ = 0; i_ < (RT_ >> 7); ++i_) {                         \
      int c_ = wid + (i_ << 3);                                                         \
      int row_ = (c_ << 4) + (lane >> 2);                                               \
      int sl_ = (lane & 3) ^ ((row_ >> 1) & 3);                                         \
      gl2lds16(src_ + qb_ + row_ * 32 + (sl_ << 3), lds_ + (c_ << 9) + (lane << 3));    \
    }                                                                                   \
  } while (0)

// one phase. WMODE: 0 none, 1 counted vmcnt, 2 vmcnt(0) (tail only)
#define PHASE(T, KC, MH, LOADB, QARG, WMODE)                                            \
  do {                                                                                  \
    const int buf_ = (T) & 1;                                                           \
    bf16x8 a4[MF / 2];                                                                  \
    _Pragma("unroll") for (int m = 0; m < MF / 2; ++m) {                                \
      int row = wr * (MF * 16) + ((MH) * (MF / 2) + m) * 16 + cl;                       \
      a4[m] = *(const bf16x8*)&Al[buf_ * (BM * 64) + (KC) * (BM * 32) + row * 32 +      \
                                  ((g ^ ((row >> 1) & 3)) << 3)];                       \
    }                                                                                   \
    if constexpr (LOADB) {                                                              \
      _Pragma("unroll") for (int n = 0; n < 4; ++n) {                                   \
        int row = (wc << 6) + (n << 4) + cl;                                            \
        bf4[n] = *(const bf16x8*)&Bl[buf_ * 16384 + (KC) * 8192 + row * 32 +            \
                                     ((g ^ ((row >> 1) & 3)) << 3)];                    \
      }                                                                                 \
    }                                                                                   \
    if constexpr ((QARG) >= 0) { STAGEQ((T) + 1, ((QARG) & 3)); }                       \
    if constexpr ((WMODE) == 1) {                                                       \
      if constexpr (MF == 8) { asm volatile("s_waitcnt vmcnt(4)" ::: "memory"); }       \
      else                   { asm volatile("s_waitcnt vmcnt(3)" ::: "memory"); }       \
    } else if constexpr ((WMODE) == 2) {                                                \
      asm volatile("s_waitcnt vmcnt(0)" ::: "memory");                                  \
    }                                                                                   \
    __builtin_amdgcn_s_barrier();                                                       \
    __builtin_amdgcn_s_setprio(1);                                                      \
    _Pragma("unroll") for (int m = 0; m < MF / 2; ++m)                                  \
      _Pragma("unroll") for (int n = 0; n < 4; ++n)                                     \
        acc[(MH) * (MF / 2) + m][n] = __builtin_amdgcn_mfma_f32_16x16x32_bf16(          \
            a4[m], bf4[n], acc[(MH) * (MF / 2) + m][n], 0, 0, 0);                       \
    __builtin_amdgcn_s_setprio(0);                                                      \
    __builtin_amdgcn_s_barrier();                                                       \
  } while (0)

  // prologue: stage all of K-tile 0, drain, barrier
  STAGEQ(0, 0); STAGEQ(0, 1); STAGEQ(0, 2); STAGEQ(0, 3);
  asm volatile("s_waitcnt vmcnt(0)" ::: "memory");
  __builtin_amdgcn_s_barrier();

  for (int t = 0; t < NKT - 1; ++t) {
    PHASE(t, 0, 0, true,  0, 0);
    PHASE(t, 0, 1, false, 1, 1);
    PHASE(t, 1, 1, true,  2, 0);
    PHASE(t, 1, 0, false, 3, 1);
  }
  {
    const int T = NKT - 1;
    PHASE(T, 0, 0, true,  -1, 0);
    PHASE(T, 0, 1, false, -1, 2);
    PHASE(T, 1, 1, true,  -1, 0);
    PHASE(T, 1, 0, false, -1, 0);
  }
#undef PHASE
#undef STAGEQ

  // epilogue
#pragma unroll
  for (int m = 0; m < MF; ++m) {
    int rbase = row0 + wr * (MF * 16) + (m << 4) + (g << 2);
#pragma unroll
    for (int n = 0; n < 4; ++n) {
      int col = col0 + (wc << 6) + (n << 4) + cl;
#pragma unroll
      for (int r = 0; r < 4; ++r) {
        float v = acc[m][n][r];
        int rr = rbase + r;
        if constexpr (MODE == 0) {
          outF[(size_t)rr * Ntot + col] = v;
        } else {  // MODE 3
          int bb = rr >> 11, ss = rr & 2047;
          if (col < 2048) {
            int hh = col >> 7, d = col & 127;
            outQ[((((size_t)bb << 4) + hh) * 2048 + ss) * 128 + d] = f2b(v + bq_[col]);
          } else if (col < 2560) {
            int c2 = col - 2048, kk = c2 >> 7, d = c2 & 127;
            outK[((((size_t)bb << 2) + kk) * 2048 + ss) * 128 + d] = f2b(v + bk_[c2]);
          } else {
            int c2 = col - 2560, kk = c2 >> 7, d = c2 & 127;
            outV[((((size_t)bb << 2) + kk) * 128 + d) * 2048 + ss] = f2b(v + bv_[c2]);
          }
        }
      }
    }
  }
}

// ---------------- flash attention: swapped QK^T, 32x32x16 MFMA ----------------
// Qb [B][16][S][128] (pre-scaled, RoPE'd), Kb [B][4][S][128], Vt [B][4][128][S]
// AOp packed [64][B*S][32] bf16 (feeds O-proj directly).
// 256 threads = 4 waves x 32 q-rows, KVBLK=64.
__global__ __launch_bounds__(256, 2) void attn2_k(
    const unsigned short* __restrict__ Qb, const unsigned short* __restrict__ Kb,
    const unsigned short* __restrict__ Vt, unsigned short* __restrict__ AOp) {
  __shared__ alignas(16) unsigned short Ks[2][64 * 128];   // [kv][d], slot^=(row&15)
  __shared__ alignas(16) unsigned short Vs[2][128 * 64];   // [d][kv], slot^=(row&7)

  const int tid = threadIdx.x, lane = tid & 63, wid = tid >> 6;
  const int hw = blockIdx.x;
  const int work = ((hw & 7) << 6) | (hw >> 3);
  const int qblk = work & 15, bh = work >> 4;
  const int b = bh >> 4, h = bh & 15, kvh = h >> 2;
  const int q0 = qblk << 7;
  const int cl = lane & 31, hi = lane >> 5;

  const unsigned short* Qp = Qb + ((size_t)(b * 16 + h) << 11) * 128;
  const unsigned short* Kp = Kb + ((size_t)(b * 4 + kvh) << 11) * 128;
  const unsigned short* Vp = Vt + ((size_t)(b * 4 + kvh) << 7) * 2048;

  const int qrow = q0 + (wid << 5) + cl;
  bf16x8 qf[8];
#pragma unroll
  for (int c = 0; c < 8; ++c)
    qf[c] = *(const bf16x8*)(Qp + (size_t)qrow * 128 + (c << 4) + (hi << 3));

  f32x16 o[4];
#pragma unroll
  for (int dt = 0; dt < 4; ++dt)
#pragma unroll
    for (int r = 0; r < 16; ++r) o[dt][r] = 0.f;
  float m = -3e38f, l = 0.f;

  auto stage = [&](int t, int buf) {
    const int kv0 = t << 6;
#pragma unroll
    for (int i = 0; i < 4; ++i) {   // K: wave stages 16 rows x 256B
      int row = (wid << 4) + (i << 2) + (lane >> 4);
      int sl = (lane & 15) ^ (row & 15);
      gl2lds16(Kp + ((size_t)(kv0 + row) << 7) + (sl << 3),
               &Ks[buf][(wid << 11) + (i << 9) + (lane << 3)]);
    }
#pragma unroll
    for (int i = 0; i < 4; ++i) {   // V^T: wave stages 32 rows x 128B
      int row = (wid << 5) + (i << 3) + (lane >> 3);
      int sl = (lane & 7) ^ (row & 7);
      gl2lds16(Vp + ((size_t)row << 11) + kv0 + (sl << 3),
               &Vs[buf][(wid << 11) + (i << 9) + (lane << 3)]);
    }
  };

  auto pack8 = [&](float a0, float a1, float a2, float a3,
                   float a4, float a5, float a6, float a7) -> u32x4 {
    u32 x0 = cvtpk_bf16(a0, a1);
    u32 y0 = cvtpk_bf16(a4, a5);
    u32 x1 = cvtpk_bf16(a2, a3);
    u32 y1 = cvtpk_bf16(a6, a7);
    pl32swap(x0, y0);
    pl32swap(x1, y1);
    return (u32x4){x0, x1, y0, y1};
  };

  stage(0, 0);
  __syncthreads();

  for (int t = 0; t < 32; ++t) {
    const int buf = t & 1;
    if (t + 1 < 32) stage(t + 1, buf ^ 1);

    f32x16 s0, s1;
#pragma unroll
    for (int r = 0; r < 16; ++r) { s0[r] = 0.f; s1[r] = 0.f; }
#pragma unroll
    for (int c = 0; c < 8; ++c) {
      int sl0 = ((c << 1) + hi) ^ (cl & 15);
      bf16x8 kf0 = *(const bf16x8*)&Ks[buf][(cl << 7) + (sl0 << 3)];
      s0 = __builtin_amdgcn_mfma_f32_32x32x16_bf16(kf0, qf[c], s0, 0, 0, 0);
    }
#pragma unroll
    for (int c = 0; c < 8; ++c) {
      int row = 32 + cl;
      int sl1 = ((c << 1) + hi) ^ (row & 15);
      bf16x8 kf1 = *(const bf16x8*)&Ks[buf][(row << 7) + (sl1 << 3)];
      s1 = __builtin_amdgcn_mfma_f32_32x32x16_bf16(kf1, qf[c], s1, 0, 0, 0);
    }

    float mx = s0[0];
#pragma unroll
    for (int r = 1; r < 16; ++r) mx = fmaxf(mx, s0[r]);
#pragma unroll
    for (int r = 0; r < 16; ++r) mx = fmaxf(mx, s1[r]);
    mx = fmaxf(mx, __shfl_xor(mx, 32));

    if (!__all(mx <= m + 8.0f)) {
      float mn = fmaxf(m, mx);
      float al = __expf(m - mn);
      m = mn;
      l *= al;
#pragma unroll
      for (int dt = 0; dt < 4; ++dt)
#pragma unroll
        for (int r = 0; r < 16; ++r) o[dt][r] *= al;
    }

    float sum = 0.f;
#pragma unroll
    for (int r = 0; r < 16; ++r) { s0[r] = __expf(s0[r] - m); sum += s0[r]; }
#pragma unroll
    for (int r = 0; r < 16; ++r) { s1[r] = __expf(s1[r] - m); sum += s1[r]; }
    l += sum;

    u32x4 w0 = pack8(s0[0], s0[1], s0[2], s0[3], s0[4], s0[5], s0[6], s0[7]);
    u32x4 w1 = pack8(s0[8], s0[9], s0[10], s0[11], s0[12], s0[13], s0[14], s0[15]);
    u32x4 w2 = pack8(s1[0], s1[1], s1[2], s1[3], s1[4], s1[5], s1[6], s1[7]);
    u32x4 w3 = pack8(s1[8], s1[9], s1[10], s1[11], s1[12], s1[13], s1[14], s1[15]);
    bf16x8 pa0 = __builtin_bit_cast(bf16x8, w0);
    bf16x8 pa1 = __builtin_bit_cast(bf16x8, w1);
    bf16x8 pa2 = __builtin_bit_cast(bf16x8, w2);
    bf16x8 pa3 = __builtin_bit_cast(bf16x8, w3);

#pragma unroll
    for (int dt = 0; dt < 4; ++dt) {
      int row = (dt << 5) + cl;
      int sb = row << 6;
      int rx = row & 7;
      bf16x8 vf0 = *(const bf16x8*)&Vs[buf][sb + (((hi) ^ rx) << 3)];
      o[dt] = __builtin_amdgcn_mfma_f32_32x32x16_bf16(vf0, pa0, o[dt], 0, 0, 0);
      bf16x8 vf1 = *(const bf16x8*)&Vs[buf][sb + (((2 + hi) ^ rx) << 3)];
      o[dt] = __builtin_amdgcn_mfma_f32_32x32x16_bf16(vf1, pa1, o[dt], 0, 0, 0);
      bf16x8 vf2 = *(const bf16x8*)&Vs[buf][sb + (((4 + hi) ^ rx) << 3)];
      o[dt] = __builtin_amdgcn_mfma_f32_32x32x16_bf16(vf2, pa2, o[dt], 0, 0, 0);
      bf16x8 vf3 = *(const bf16x8*)&Vs[buf][sb + (((6 + hi) ^ rx) << 3)];
      o[dt] = __builtin_amdgcn_mfma_f32_32x32x16_bf16(vf3, pa3, o[dt], 0, 0, 0);
    }
    __syncthreads();
  }

  // write packed AO: feature c = h*128 + dt*32 + rq*8 + hi*4 + j -> panel h*4+dt
  float inv = 1.0f / (l + __shfl_xor(l, 32));
  const int rowi = b * 2048 + qrow;
#pragma unroll
  for (int dt = 0; dt < 4; ++dt) {
    unsigned short* base = AOp + (((size_t)((h << 2) + dt)) * 4096 + rowi) * 32;
#pragma unroll
    for (int rq = 0; rq < 4; ++rq) {
      u16x4 pk = { f2b(o[dt][(rq << 2) + 0] * inv), f2b(o[dt][(rq << 2) + 1] * inv),
                   f2b(o[dt][(rq << 2) + 2] * inv), f2b(o[dt][(rq << 2) + 3] * inv) };
      *(u16x4*)(base + (rq << 3) + (hi << 2)) = pk;
    }
  }
}

// ---------------- launch ----------------
extern "C" void kernel_launch(void* const* d_in, const int* in_sizes, int n_in,
                              void* d_out, int out_size, void* d_ws, size_t ws_size,
                              hipStream_t stream) {
  const float* X  = (const float*)d_in[0];
  const float* Wq = (const float*)d_in[1];
  const float* bq = (const float*)d_in[2];
  const float* Wk = (const float*)d_in[3];
  const float* bk = (const float*)d_in[4];
  const float* Wv = (const float*)d_in[5];
  const float* bv = (const float*)d_in[6];
  const float* Wo = (const float*)d_in[7];
  float* out = (float*)d_out;

  char* ws = (char*)d_ws;
  size_t off = 0;
  auto alloc = [&](size_t bytes) {
    char* p = ws + off;
    off += (bytes + 255) & ~(size_t)255;
    return p;
  };
  unsigned short* Xp   = (unsigned short*)alloc(4096ull * 2048 * 2);   // packed [64][4096][32]
  unsigned short* Wcat = (unsigned short*)alloc(3072ull * 2048 * 2);   // packed [64][3072][32]
  unsigned short* Wop  = (unsigned short*)alloc(2048ull * 2048 * 2);   // packed [64][2048][32]
  unsigned short* Qb   = (unsigned short*)alloc(2ull * 16 * 2048 * 128 * 2);
  unsigned short* Kb   = (unsigned short*)alloc(2ull * 4 * 2048 * 128 * 2);
  unsigned short* Vt   = (unsigned short*)alloc(2ull * 4 * 128 * 2048 * 2);
  unsigned short* AOp  = (unsigned short*)alloc(4096ull * 2048 * 2);   // packed [64][4096][32]
  float* ctab = (float*)alloc(2048ull * 64 * 4);
  float* stab = (float*)alloc(2048ull * 64 * 4);

  rope_tables_k<<<dim3(2048), dim3(64), 0, stream>>>(ctab, stab);
  packX_k<<<dim3(4096), dim3(256), 0, stream>>>(X, Xp, 4096);
  packW_k<<<dim3(64, 64), dim3(32, 8), 0, stream>>>(Wq, Wcat, 2048, 3072, 0);
  packW_k<<<dim3(16, 64), dim3(32, 8), 0, stream>>>(Wk, Wcat, 512, 3072, 2048);
  packW_k<<<dim3(16, 64), dim3(32, 8), 0, stream>>>(Wv, Wcat, 512, 3072, 2560);
  packW_k<<<dim3(64, 64), dim3(32, 8), 0, stream>>>(Wo, Wop, 2048, 2048, 0);

  // fused QKV projection: M=4096, N=3072, K=2048. BM=BN=256 -> 192 blocks.
  gemm8p_k<8, 3><<<dim3(192), dim3(512), 0, stream>>>(
      Xp, Wcat, nullptr, Qb, Kb, Vt, bq, bk, bv, 4096, 3072, 12);

  rope8_k<true><<<dim3(2048), dim3(256), 0, stream>>>(Qb, ctab, stab, 524288);
  rope8_k<false><<<dim3(512), dim3(256), 0, stream>>>(Kb, ctab, stab, 131072);

  attn2_k<<<dim3(512), dim3(256), 0, stream>>>(Qb, Kb, Vt, AOp);

  // O projection: M=4096, N=2048, K=2048. BM=128, BN=256 -> 256 blocks (1/CU).
  gemm8p_k<4, 0><<<dim3(256), dim3(512), 0, stream>>>(
      AOp, Wop, out, nullptr, nullptr, nullptr, nullptr, nullptr, nullptr, 4096, 2048, 8);
}

// Round 6
// 244.011 us; speedup vs baseline: 1.1844x; 1.1815x over previous
//
#include <hip/hip_runtime.h>
#include <stdint.h>
#include <math.h>

typedef unsigned int u32;
typedef __bf16 bf16x8 __attribute__((ext_vector_type(8)));
typedef float  f32x4  __attribute__((ext_vector_type(4)));
typedef float  f32x16 __attribute__((ext_vector_type(16)));
typedef unsigned int u32x4 __attribute__((ext_vector_type(4)));
typedef unsigned short u16x4 __attribute__((ext_vector_type(4)));
typedef unsigned short u16x8 __attribute__((ext_vector_type(8)));

#define DEV __device__ __forceinline__

DEV unsigned short f2b(float f) {
  u32 x = __builtin_bit_cast(u32, f);
  u32 r = (x + 0x7fffu + ((x >> 16) & 1u)) >> 16;
  return (unsigned short)r;
}
DEV float b2f(unsigned short u) { return __builtin_bit_cast(float, ((u32)u) << 16); }

DEV u32 cvtpk_bf16(float lo, float hi) {
  u32 r;
  asm("v_cvt_pk_bf16_f32 %0, %1, %2" : "=v"(r) : "v"(lo), "v"(hi));
  return r;
}
DEV void pl32swap(u32& a, u32& b) {
  asm("v_permlane32_swap_b32 %0, %1" : "+v"(a), "+v"(b));
}

// async global->LDS, 16B per lane. LDS dest = wave-uniform base + lane*16.
DEV void gl2lds16(const void* g, void* l) {
  __builtin_amdgcn_global_load_lds((const __attribute__((address_space(1))) u32*)g,
                                   (__attribute__((address_space(3))) u32*)l, 16, 0, 0);
}

// ---------------- prep kernels ----------------

__global__ void rope_tables_k(float* __restrict__ ct, float* __restrict__ st) {
  int s = blockIdx.x;          // 0..2047
  int d = threadIdx.x;         // 0..63
  float inv = powf(10000.0f, -(float)d / 64.0f);
  float a = (float)s * inv;
  ct[s * 64 + d] = cosf(a);
  st[s * 64 + d] = sinf(a);
}

// X f32 [Mtot][2048] -> packed bf16 [64][Mtot][32]
__global__ void packX_k(const float* __restrict__ in, unsigned short* __restrict__ out,
                        int Mtot) {
  int i = blockIdx.x * blockDim.x + threadIdx.x;   // one thread per 8 elems
  int k8 = i & 255;          // 2048/8 octets per row
  int m = i >> 8;
  if (m >= Mtot) return;
  const float4* p = (const float4*)(in + (size_t)m * 2048 + (k8 << 3));
  float4 v0 = p[0], v1 = p[1];
  u16x8 r = { f2b(v0.x), f2b(v0.y), f2b(v0.z), f2b(v0.w),
              f2b(v1.x), f2b(v1.y), f2b(v1.z), f2b(v1.w) };
  int kt = k8 >> 2;          // (k8*8)>>5
  int ko = (k8 & 3) << 3;    // (k8*8)&31
  *(u16x8*)(out + ((size_t)kt * Mtot + m) * 32 + ko) = r;
}

// W f32 [2048][Nd] -> packed bf16 [64][Ncat][32] (transposed), cols at ncOff
__global__ void packW_k(const float* __restrict__ in, unsigned short* __restrict__ out,
                        int Nd, int Ncat, int ncOff) {
  __shared__ float t[32][33];
  int n0 = blockIdx.x << 5, k0 = blockIdx.y << 5;
  int tx = threadIdx.x, ty = threadIdx.y;  // 32 x 8
  for (int i = ty; i < 32; i += 8) t[i][tx] = in[(size_t)(k0 + i) * Nd + n0 + tx];
  __syncthreads();
  for (int i = ty; i < 32; i += 8)
    out[((size_t)(k0 >> 5) * Ncat + ncOff + n0 + i) * 32 + tx] = f2b(t[tx][i]);
}

// vectorized RoPE: each thread handles 8 d-values (pair d, d+64), 16B loads
template <bool SC>
__global__ void rope8_k(unsigned short* __restrict__ p, const float* __restrict__ ct,
                        const float* __restrict__ st, int total) {
  int i = blockIdx.x * blockDim.x + threadIdx.x;
  if (i >= total) return;
  int j = i & 7;               // which 8-wide d block in [0,64)
  int s = (i >> 3) & 2047;
  int bh = i >> 14;
  size_t base = ((size_t)bh * 2048 + s) * 128 + (j << 3);
  u16x8 a = *(const u16x8*)(p + base);
  u16x8 b = *(const u16x8*)(p + base + 64);
  const float* cp = ct + s * 64 + (j << 3);
  const float* sp = st + s * 64 + (j << 3);
  u16x8 oa, ob;
#pragma unroll
  for (int e = 0; e < 8; ++e) {
    float x1 = b2f(a[e]), x2 = b2f(b[e]);
    float c = cp[e], sn = sp[e];
    float o1 = x1 * c - x2 * sn;
    float o2 = x2 * c + x1 * sn;
    if (SC) { o1 *= 0.08838834764831845f; o2 *= 0.08838834764831845f; }
    oa[e] = f2b(o1);
    ob[e] = f2b(o2);
  }
  *(u16x8*)(p + base) = oa;
  *(u16x8*)(p + base + 64) = ob;
}

// ---------------- GEMM: 128x128 tile, BK=32, 4-deep ring, 2 blocks/CU ----------------
// A packed [K/32][Mtot][32] bf16, B packed [K/32][Ntot][32] bf16, K=2048 (64 steps).
// 256 threads = 4 waves (2M x 2N); per wave 64x64 out = 4x4 frags, 16 MFMA/step.
// LDS: 4 ring slots per operand of [128][32] (8KB) = 64 KiB total -> 2 blocks/CU.
// Per step: 8 ds_read_b128 | stage piece s+3 (4 gl2lds, 1KB contiguous chunks) |
// setprio(1) 16 MFMA setprio(0) | vmcnt(8) (retire piece s+1, issued 3 steps ago)
// | s_barrier. Counted vmcnt never drains mid-loop; 2 resident blocks/CU cover
// the residual stalls (m114 overlap mechanism).
// MODE 0: fp32 out[row*Ntot+col].  MODE 3: fused QKV epilogue.
template <int MODE, int GX>
__global__ __launch_bounds__(256, 2) void gemm128_k(
    const unsigned short* __restrict__ Ap, const unsigned short* __restrict__ Bp,
    float* __restrict__ outF, unsigned short* __restrict__ outQ,
    unsigned short* __restrict__ outK, unsigned short* __restrict__ outV,
    const float* __restrict__ bq_, const float* __restrict__ bk_,
    const float* __restrict__ bv_, int Mtot, int Ntot) {
  constexpr int NST = 64;                                  // K=2048 / BK=32
  __shared__ alignas(16) unsigned short Al[4 * 128 * 32];  // 32 KB ring
  __shared__ alignas(16) unsigned short Bl[4 * 128 * 32];  // 32 KB ring

  const int tid = threadIdx.x, lane = tid & 63, wid = tid >> 6;
  const int wm = wid >> 1, wn = wid & 1;
  const int cl = lane & 15, g = lane >> 4;

  // XCD-grouped mapping: xcd = bid&7 owns 4 consecutive M-rows of panels ->
  // A panels (2MB) resident in that XCD's L2; B panels reused 4x within XCD.
  const int bid = blockIdx.x;
  const int by = ((bid & 7) << 2) + ((bid >> 3) / GX);
  const int bx = (bid >> 3) % GX;
  const int row0 = by << 7, col0 = bx << 7;

  // staging geometry: piece = 128 rows x 64B = 8 chunks of 1KB; wave handles 2.
  const int c0 = wid, c1 = wid + 4;
  const int sr0 = (c0 << 4) + (lane >> 2);
  const int sr1 = (c1 << 4) + (lane >> 2);
  const int sl0 = (lane & 3) ^ ((sr0 >> 1) & 3);   // pre-permuted source = LDS swizzle
  const int sl1 = (lane & 3) ^ ((sr1 >> 1) & 3);
  const size_t dA = (size_t)Mtot * 32, dB = (size_t)Ntot * 32;
  const unsigned short* pa0 = Ap + (size_t)(row0 + sr0) * 32 + (sl0 << 3);
  const unsigned short* pa1 = Ap + (size_t)(row0 + sr1) * 32 + (sl1 << 3);
  const unsigned short* pb0 = Bp + (size_t)(col0 + sr0) * 32 + (sl0 << 3);
  const unsigned short* pb1 = Bp + (size_t)(col0 + sr1) * 32 + (sl1 << 3);
  const int ld0 = (c0 << 9) + (lane << 3);         // u16 offset within ring slot
  const int ld1 = (c1 << 9) + (lane << 3);

  int sslot = 0;   // ring slot of next piece to stage
  auto stage = [&]() {
    const int bb = sslot << 12;
    gl2lds16(pa0, &Al[bb + ld0]);
    gl2lds16(pa1, &Al[bb + ld1]);
    gl2lds16(pb0, &Bl[bb + ld0]);
    gl2lds16(pb1, &Bl[bb + ld1]);
    pa0 += dA; pa1 += dA; pb0 += dB; pb1 += dB;
    sslot = (sslot + 1) & 3;
  };

  // ds_read fragment offsets (constant per thread; + ring-slot base per step)
  int aoff[4], boff[4];
#pragma unroll
  for (int m = 0; m < 4; ++m) {
    int row = (wm << 6) + (m << 4) + cl;
    aoff[m] = (row << 5) + ((g ^ ((row >> 1) & 3)) << 3);
    row = (wn << 6) + (m << 4) + cl;
    boff[m] = (row << 5) + ((g ^ ((row >> 1) & 3)) << 3);
  }

  f32x4 acc[4][4];
#pragma unroll
  for (int m = 0; m < 4; ++m)
#pragma unroll
    for (int n = 0; n < 4; ++n) acc[m][n] = (f32x4){0.f, 0.f, 0.f, 0.f};

#define STEP(S, DO_STAGE)                                                          \
  do {                                                                             \
    const int bb_ = ((S) & 3) << 12;                                               \
    bf16x8 af[4], bfr[4];                                                          \
    _Pragma("unroll") for (int m = 0; m < 4; ++m)                                  \
        af[m] = *(const bf16x8*)&Al[bb_ + aoff[m]];                                \
    _Pragma("unroll") for (int n = 0; n < 4; ++n)                                  \
        bfr[n] = *(const bf16x8*)&Bl[bb_ + boff[n]];                               \
    if (DO_STAGE) stage();                                                         \
    __builtin_amdgcn_s_setprio(1);                                                 \
    _Pragma("unroll") for (int m = 0; m < 4; ++m)                                  \
      _Pragma("unroll") for (int n = 0; n < 4; ++n)                                \
        acc[m][n] = __builtin_amdgcn_mfma_f32_16x16x32_bf16(af[m], bfr[n],         \
                                                            acc[m][n], 0, 0, 0);  \
    __builtin_amdgcn_s_setprio(0);                                                 \
  } while (0)

  // prologue: pieces 0,1,2 in flight (12 instr); wait piece 0 (retire 4)
  stage(); stage(); stage();
  asm volatile("s_waitcnt vmcnt(8)" ::: "memory");
  __builtin_amdgcn_s_barrier();

  for (int s = 0; s < NST - 3; ++s) {      // steps 0..60: stage s+3, keep 8 in flight
    STEP(s, true);
    asm volatile("s_waitcnt vmcnt(8)" ::: "memory");
    __builtin_amdgcn_s_barrier();
  }
  STEP(NST - 3, false);
  asm volatile("s_waitcnt vmcnt(4)" ::: "memory");
  __builtin_amdgcn_s_barrier();
  STEP(NST - 2, false);
  asm volatile("s_waitcnt vmcnt(0)" ::: "memory");
  __builtin_amdgcn_s_barrier();
  STEP(NST - 1, false);
#undef STEP

  // epilogue
#pragma unroll
  for (int mt = 0; mt < 4; ++mt) {
    int rbase = row0 + (wm << 6) + (mt << 4) + (g << 2);
#pragma unroll
    for (int nt = 0; nt < 4; ++nt) {
      int col = col0 + (wn << 6) + (nt << 4) + cl;
#pragma unroll
      for (int r = 0; r < 4; ++r) {
        float v = acc[mt][nt][r];
        int rr = rbase + r;
        if constexpr (MODE == 0) {
          outF[(size_t)rr * Ntot + col] = v;
        } else {  // MODE 3
          int bb = rr >> 11, ss = rr & 2047;
          if (col < 2048) {
            int hh = col >> 7, d = col & 127;
            outQ[((((size_t)bb << 4) + hh) * 2048 + ss) * 128 + d] = f2b(v + bq_[col]);
          } else if (col < 2560) {
            int c2 = col - 2048, kk = c2 >> 7, d = c2 & 127;
            outK[((((size_t)bb << 2) + kk) * 2048 + ss) * 128 + d] = f2b(v + bk_[c2]);
          } else {
            int c2 = col - 2560, kk = c2 >> 7, d = c2 & 127;
            outV[((((size_t)bb << 2) + kk) * 128 + d) * 2048 + ss] = f2b(v + bv_[c2]);
          }
        }
      }
    }
  }
}

// ---------------- flash attention: swapped QK^T, 32x32x16 MFMA ----------------
// Qb [B][16][S][128] (pre-scaled, RoPE'd), Kb [B][4][S][128], Vt [B][4][128][S]
// AOp packed [64][B*S][32] bf16 (feeds O-proj directly).
// 256 threads = 4 waves x 32 q-rows, KVBLK=64.
__global__ __launch_bounds__(256, 2) void attn2_k(
    const unsigned short* __restrict__ Qb, const unsigned short* __restrict__ Kb,
    const unsigned short* __restrict__ Vt, unsigned short* __restrict__ AOp) {
  __shared__ alignas(16) unsigned short Ks[2][64 * 128];   // [kv][d], slot^=(row&15)
  __shared__ alignas(16) unsigned short Vs[2][128 * 64];   // [d][kv], slot^=(row&7)

  const int tid = threadIdx.x, lane = tid & 63, wid = tid >> 6;
  const int hw = blockIdx.x;
  const int work = ((hw & 7) << 6) | (hw >> 3);
  const int qblk = work & 15, bh = work >> 4;
  const int b = bh >> 4, h = bh & 15, kvh = h >> 2;
  const int q0 = qblk << 7;
  const int cl = lane & 31, hi = lane >> 5;

  const unsigned short* Qp = Qb + ((size_t)(b * 16 + h) << 11) * 128;
  const unsigned short* Kp = Kb + ((size_t)(b * 4 + kvh) << 11) * 128;
  const unsigned short* Vp = Vt + ((size_t)(b * 4 + kvh) << 7) * 2048;

  const int qrow = q0 + (wid << 5) + cl;
  bf16x8 qf[8];
#pragma unroll
  for (int c = 0; c < 8; ++c)
    qf[c] = *(const bf16x8*)(Qp + (size_t)qrow * 128 + (c << 4) + (hi << 3));

  f32x16 o[4];
#pragma unroll
  for (int dt = 0; dt < 4; ++dt)
#pragma unroll
    for (int r = 0; r < 16; ++r) o[dt][r] = 0.f;
  float m = -3e38f, l = 0.f;

  auto stage = [&](int t, int buf) {
    const int kv0 = t << 6;
#pragma unroll
    for (int i = 0; i < 4; ++i) {   // K: wave stages 16 rows x 256B
      int row = (wid << 4) + (i << 2) + (lane >> 4);
      int sl = (lane & 15) ^ (row & 15);
      gl2lds16(Kp + ((size_t)(kv0 + row) << 7) + (sl << 3),
               &Ks[buf][(wid << 11) + (i << 9) + (lane << 3)]);
    }
#pragma unroll
    for (int i = 0; i < 4; ++i) {   // V^T: wave stages 32 rows x 128B
      int row = (wid << 5) + (i << 3) + (lane >> 3);
      int sl = (lane & 7) ^ (row & 7);
      gl2lds16(Vp + ((size_t)row << 11) + kv0 + (sl << 3),
               &Vs[buf][(wid << 11) + (i << 9) + (lane << 3)]);
    }
  };

  auto pack8 = [&](float a0, float a1, float a2, float a3,
                   float a4, float a5, float a6, float a7) -> u32x4 {
    u32 x0 = cvtpk_bf16(a0, a1);
    u32 y0 = cvtpk_bf16(a4, a5);
    u32 x1 = cvtpk_bf16(a2, a3);
    u32 y1 = cvtpk_bf16(a6, a7);
    pl32swap(x0, y0);
    pl32swap(x1, y1);
    return (u32x4){x0, x1, y0, y1};
  };

  stage(0, 0);
  __syncthreads();

  for (int t = 0; t < 32; ++t) {
    const int buf = t & 1;
    if (t + 1 < 32) stage(t + 1, buf ^ 1);

    f32x16 s0, s1;
#pragma unroll
    for (int r = 0; r < 16; ++r) { s0[r] = 0.f; s1[r] = 0.f; }
#pragma unroll
    for (int c = 0; c < 8; ++c) {
      int sl0 = ((c << 1) + hi) ^ (cl & 15);
      bf16x8 kf0 = *(const bf16x8*)&Ks[buf][(cl << 7) + (sl0 << 3)];
      s0 = __builtin_amdgcn_mfma_f32_32x32x16_bf16(kf0, qf[c], s0, 0, 0, 0);
    }
#pragma unroll
    for (int c = 0; c < 8; ++c) {
      int row = 32 + cl;
      int sl1 = ((c << 1) + hi) ^ (row & 15);
      bf16x8 kf1 = *(const bf16x8*)&Ks[buf][(row << 7) + (sl1 << 3)];
      s1 = __builtin_amdgcn_mfma_f32_32x32x16_bf16(kf1, qf[c], s1, 0, 0, 0);
    }

    float mx = s0[0];
#pragma unroll
    for (int r = 1; r < 16; ++r) mx = fmaxf(mx, s0[r]);
#pragma unroll
    for (int r = 0; r < 16; ++r) mx = fmaxf(mx, s1[r]);
    mx = fmaxf(mx, __shfl_xor(mx, 32));

    if (!__all(mx <= m + 8.0f)) {
      float mn = fmaxf(m, mx);
      float al = __expf(m - mn);
      m = mn;
      l *= al;
#pragma unroll
      for (int dt = 0; dt < 4; ++dt)
#pragma unroll
        for (int r = 0; r < 16; ++r) o[dt][r] *= al;
    }

    float sum = 0.f;
#pragma unroll
    for (int r = 0; r < 16; ++r) { s0[r] = __expf(s0[r] - m); sum += s0[r]; }
#pragma unroll
    for (int r = 0; r < 16; ++r) { s1[r] = __expf(s1[r] - m); sum += s1[r]; }
    l += sum;

    u32x4 w0 = pack8(s0[0], s0[1], s0[2], s0[3], s0[4], s0[5], s0[6], s0[7]);
    u32x4 w1 = pack8(s0[8], s0[9], s0[10], s0[11], s0[12], s0[13], s0[14], s0[15]);
    u32x4 w2 = pack8(s1[0], s1[1], s1[2], s1[3], s1[4], s1[5], s1[6], s1[7]);
    u32x4 w3 = pack8(s1[8], s1[9], s1[10], s1[11], s1[12], s1[13], s1[14], s1[15]);
    bf16x8 pa0 = __builtin_bit_cast(bf16x8, w0);
    bf16x8 pa1 = __builtin_bit_cast(bf16x8, w1);
    bf16x8 pa2 = __builtin_bit_cast(bf16x8, w2);
    bf16x8 pa3 = __builtin_bit_cast(bf16x8, w3);

#pragma unroll
    for (int dt = 0; dt < 4; ++dt) {
      int row = (dt << 5) + cl;
      int sb = row << 6;
      int rx = row & 7;
      bf16x8 vf0 = *(const bf16x8*)&Vs[buf][sb + (((hi) ^ rx) << 3)];
      o[dt] = __builtin_amdgcn_mfma_f32_32x32x16_bf16(vf0, pa0, o[dt], 0, 0, 0);
      bf16x8 vf1 = *(const bf16x8*)&Vs[buf][sb + (((2 + hi) ^ rx) << 3)];
      o[dt] = __builtin_amdgcn_mfma_f32_32x32x16_bf16(vf1, pa1, o[dt], 0, 0, 0);
      bf16x8 vf2 = *(const bf16x8*)&Vs[buf][sb + (((4 + hi) ^ rx) << 3)];
      o[dt] = __builtin_amdgcn_mfma_f32_32x32x16_bf16(vf2, pa2, o[dt], 0, 0, 0);
      bf16x8 vf3 = *(const bf16x8*)&Vs[buf][sb + (((6 + hi) ^ rx) << 3)];
      o[dt] = __builtin_amdgcn_mfma_f32_32x32x16_bf16(vf3, pa3, o[dt], 0, 0, 0);
    }
    __syncthreads();
  }

  // write packed AO: feature c = h*128 + dt*32 + rq*8 + hi*4 + j -> panel h*4+dt
  float inv = 1.0f / (l + __shfl_xor(l, 32));
  const int rowi = b * 2048 + qrow;
#pragma unroll
  for (int dt = 0; dt < 4; ++dt) {
    unsigned short* base = AOp + (((size_t)((h << 2) + dt)) * 4096 + rowi) * 32;
#pragma unroll
    for (int rq = 0; rq < 4; ++rq) {
      u16x4 pk = { f2b(o[dt][(rq << 2) + 0] * inv), f2b(o[dt][(rq << 2) + 1] * inv),
                   f2b(o[dt][(rq << 2) + 2] * inv), f2b(o[dt][(rq << 2) + 3] * inv) };
      *(u16x4*)(base + (rq << 3) + (hi << 2)) = pk;
    }
  }
}

// ---------------- launch ----------------
extern "C" void kernel_launch(void* const* d_in, const int* in_sizes, int n_in,
                              void* d_out, int out_size, void* d_ws, size_t ws_size,
                              hipStream_t stream) {
  const float* X  = (const float*)d_in[0];
  const float* Wq = (const float*)d_in[1];
  const float* bq = (const float*)d_in[2];
  const float* Wk = (const float*)d_in[3];
  const float* bk = (const float*)d_in[4];
  const float* Wv = (const float*)d_in[5];
  const float* bv = (const float*)d_in[6];
  const float* Wo = (const float*)d_in[7];
  float* out = (float*)d_out;

  char* ws = (char*)d_ws;
  size_t off = 0;
  auto alloc = [&](size_t bytes) {
    char* p = ws + off;
    off += (bytes + 255) & ~(size_t)255;
    return p;
  };
  unsigned short* Xp   = (unsigned short*)alloc(4096ull * 2048 * 2);   // packed [64][4096][32]
  unsigned short* Wcat = (unsigned short*)alloc(3072ull * 2048 * 2);   // packed [64][3072][32]
  unsigned short* Wop  = (unsigned short*)alloc(2048ull * 2048 * 2);   // packed [64][2048][32]
  unsigned short* Qb   = (unsigned short*)alloc(2ull * 16 * 2048 * 128 * 2);
  unsigned short* Kb   = (unsigned short*)alloc(2ull * 4 * 2048 * 128 * 2);
  unsigned short* Vt   = (unsigned short*)alloc(2ull * 4 * 128 * 2048 * 2);
  unsigned short* AOp  = (unsigned short*)alloc(4096ull * 2048 * 2);   // packed [64][4096][32]
  float* ctab = (float*)alloc(2048ull * 64 * 4);
  float* stab = (float*)alloc(2048ull * 64 * 4);

  rope_tables_k<<<dim3(2048), dim3(64), 0, stream>>>(ctab, stab);
  packX_k<<<dim3(4096), dim3(256), 0, stream>>>(X, Xp, 4096);
  packW_k<<<dim3(64, 64), dim3(32, 8), 0, stream>>>(Wq, Wcat, 2048, 3072, 0);
  packW_k<<<dim3(16, 64), dim3(32, 8), 0, stream>>>(Wk, Wcat, 512, 3072, 2048);
  packW_k<<<dim3(16, 64), dim3(32, 8), 0, stream>>>(Wv, Wcat, 512, 3072, 2560);
  packW_k<<<dim3(64, 64), dim3(32, 8), 0, stream>>>(Wo, Wop, 2048, 2048, 0);

  // fused QKV projection: M=4096, N=3072, K=2048. 128^2 tiles -> 32x24 = 768 blocks.
  gemm128_k<3, 24><<<dim3(768), dim3(256), 0, stream>>>(
      Xp, Wcat, nullptr, Qb, Kb, Vt, bq, bk, bv, 4096, 3072);

  rope8_k<true><<<dim3(2048), dim3(256), 0, stream>>>(Qb, ctab, stab, 524288);
  rope8_k<false><<<dim3(512), dim3(256), 0, stream>>>(Kb, ctab, stab, 131072);

  attn2_k<<<dim3(512), dim3(256), 0, stream>>>(Qb, Kb, Vt, AOp);

  // O projection: M=4096, N=2048, K=2048. 32x16 = 512 blocks (2/CU).
  gemm128_k<0, 16><<<dim3(512), dim3(256), 0, stream>>>(
      AOp, Wop, out, nullptr, nullptr, nullptr, nullptr, nullptr, nullptr, 4096, 2048);
}